// Round 1
// baseline (879.233 us; speedup 1.0000x reference)
//
#include <hip/hip_runtime.h>

// SwinV2 window attention, fully fused: one block = one window (64 tokens x 192 dim).
// bf16 MFMA (16x16x32) for QKV / QK^T / PV / proj; f32 softmax + normalization.
// LDS: Xs (x staging, reused for attn output O) + QKVs + per-wave P tiles = 111,616 B.

#define LDA 200   // padded row stride (ushorts) for 192-wide tiles: 400B = 100 dwords -> 2-way bank aliasing only
#define LDP 72    // padded row stride for 64-wide P tiles: 144B, 16B-aligned rows

typedef __attribute__((ext_vector_type(4))) float floatx4;
typedef __attribute__((ext_vector_type(8))) short shortx8;
typedef __attribute__((ext_vector_type(4))) unsigned short ushortx4;

__device__ __forceinline__ unsigned short f2bf(float f) {
    union { float f; unsigned u; } v; v.f = f;
    return (unsigned short)((v.u + 0x7fffu + ((v.u >> 16) & 1u)) >> 16);  // RNE
}
__device__ __forceinline__ float bf2f(unsigned short s) {
    union { unsigned u; float f; } v; v.u = ((unsigned)s) << 16;
    return v.f;
}

// ---------------- prep: weights -> bf16, qkv bias concat ----------------
__global__ void prep_weights(const float* __restrict__ qkv_w,
                             const float* __restrict__ proj_w,
                             const float* __restrict__ q_bias,
                             const float* __restrict__ v_bias,
                             unsigned short* __restrict__ qkvw_bf,
                             unsigned short* __restrict__ projw_bf,
                             float* __restrict__ qkvb) {
    int stride = gridDim.x * blockDim.x;
    for (int i = blockIdx.x * blockDim.x + threadIdx.x; i < 110592 + 36864 + 576; i += stride) {
        if (i < 110592) {
            qkvw_bf[i] = f2bf(qkv_w[i]);
        } else if (i < 110592 + 36864) {
            projw_bf[i - 110592] = f2bf(proj_w[i - 110592]);
        } else {
            int j = i - 110592 - 36864;
            qkvb[j] = (j < 192) ? q_bias[j] : (j < 384 ? 0.f : v_bias[j - 384]);
        }
    }
}

// ---------------- prep: CPB MLP -> rpb[6][64][64] = 16*sigmoid(gather) ----------------
__global__ void prep_cpb(const float* __restrict__ w1, const float* __restrict__ b1,
                         const float* __restrict__ w2, const float* __restrict__ rct,
                         const int* __restrict__ rpi, float* __restrict__ rpb) {
    __shared__ float w1s[1024], b1s[512], w2s[3072], tbls[1350];
    int tid = threadIdx.x;
    for (int i = tid; i < 1024; i += 256) w1s[i] = w1[i];
    for (int i = tid; i < 512;  i += 256) b1s[i] = b1[i];
    for (int i = tid; i < 3072; i += 256) w2s[i] = w2[i];
    __syncthreads();
    for (int pr = tid; pr < 1350; pr += 256) {   // 225 positions x 6 heads
        int p = pr / 6, h = pr - p * 6;
        float c0 = rct[p * 2], c1 = rct[p * 2 + 1];
        float s = 0.f;
        for (int j = 0; j < 512; ++j) {
            float hv = fmaxf(0.f, c0 * w1s[j * 2] + c1 * w1s[j * 2 + 1] + b1s[j]);
            s += hv * w2s[h * 512 + j];
        }
        tbls[pr] = s;                            // [p][h]
    }
    __syncthreads();
    // rel_pos_index may arrive as int64 (little-endian pairs) or int32; value[1]==111 if int32.
    int stride64 = (rpi[1] == 0) ? 2 : 1;
    for (int e = tid; e < 24576; e += 256) {     // [h][row][col]
        int h = e >> 12, rc = e & 4095;
        int idx = rpi[rc * stride64];
        float t = tbls[idx * 6 + h];
        rpb[e] = 16.f / (1.f + __expf(-t));
    }
}

// ---------------- main fused kernel ----------------
__global__ __launch_bounds__(256, 1) void win_attn(
    const float* __restrict__ x, const float* __restrict__ mask,
    const float* __restrict__ logit_scale,
    const unsigned short* __restrict__ qkvw, const unsigned short* __restrict__ projw,
    const float* __restrict__ qkvb, const float* __restrict__ projb,
    const float* __restrict__ rpb, float* __restrict__ out)
{
    __shared__ unsigned short Xs[64 * LDA];        // 25,600 B: x staging, later attn output O
    __shared__ unsigned short QKVs[3][64 * LDA];   // 76,800 B: q,k,v  [part][token][dim]
    __shared__ unsigned short Ps[4][16 * LDP];     //  9,216 B: per-wave 16x64 P tile

    const int tid  = threadIdx.x;
    const int b    = blockIdx.x;
    const int wave = tid >> 6, lane = tid & 63;
    const int c = lane & 15, qd = lane >> 4;       // MFMA lane coords: col / quad

    // ---- Phase 0: stage x window (f32 -> bf16 LDS) ----
    {
        const float4* xw = (const float4*)(x + (size_t)b * 12288);
        for (int i = tid; i < 3072; i += 256) {
            float4 v = xw[i];
            int token = i / 48, c4 = (i - token * 48) * 4;
            ushortx4 u = { f2bf(v.x), f2bf(v.y), f2bf(v.z), f2bf(v.w) };
            *(ushortx4*)&Xs[token * LDA + c4] = u;
        }
    }
    __syncthreads();

    // ---- Phase 1: QKV GEMM (64x192)@(192x576), waves split n; weights read once/block ----
    {
        shortx8 af[4][6];                          // A frags: all 4 m-tiles x 6 k-steps
        #pragma unroll
        for (int mt = 0; mt < 4; ++mt)
            #pragma unroll
            for (int ks = 0; ks < 6; ++ks)
                af[mt][ks] = *(const shortx8*)&Xs[(mt * 16 + c) * LDA + ks * 32 + qd * 8];
        for (int nti = 0; nti < 9; ++nti) {
            int nt = wave * 9 + nti;
            const unsigned short* bp = qkvw + (nt * 16 + c) * 192 + qd * 8;
            shortx8 bf[6];
            #pragma unroll
            for (int ks = 0; ks < 6; ++ks) bf[ks] = *(const shortx8*)(bp + ks * 32);
            floatx4 acc[4];
            #pragma unroll
            for (int mt = 0; mt < 4; ++mt) acc[mt] = (floatx4){0.f, 0.f, 0.f, 0.f};
            #pragma unroll
            for (int ks = 0; ks < 6; ++ks)
                #pragma unroll
                for (int mt = 0; mt < 4; ++mt)
                    acc[mt] = __builtin_amdgcn_mfma_f32_16x16x32_bf16(af[mt][ks], bf[ks], acc[mt], 0, 0, 0);
            int gcol = nt * 16 + c;
            int part = nt / 12;                    // 0=q, 1=k, 2=v
            int inner = gcol - part * 192;
            float bias = qkvb[gcol];
            #pragma unroll
            for (int mt = 0; mt < 4; ++mt)
                #pragma unroll
                for (int r = 0; r < 4; ++r)        // C/D layout: row = qd*4+r, col = c
                    QKVs[part][(mt * 16 + qd * 4 + r) * LDA + inner] = f2bf(acc[mt][r] + bias);
        }
    }
    __syncthreads();

    // ---- Phase 2: L2-normalize q,k per (head, token); fold exp(min(ls, ln100)) into q ----
    {
        for (int idx = tid; idx < 768; idx += 256) {   // 2 parts x 6 heads x 64 tokens
            int pqk = idx / 384, rem = idx - pqk * 384;
            int h = rem >> 6, token = rem & 63;
            unsigned short* p = &QKVs[pqk][token * LDA + h * 32];
            shortx8 v0 = *(shortx8*)(p),      v1 = *(shortx8*)(p + 8),
                    v2 = *(shortx8*)(p + 16), v3 = *(shortx8*)(p + 24);
            float s = 0.f;
            #pragma unroll
            for (int j = 0; j < 8; ++j) {
                float f0 = bf2f((unsigned short)v0[j]), f1 = bf2f((unsigned short)v1[j]);
                float f2 = bf2f((unsigned short)v2[j]), f3 = bf2f((unsigned short)v3[j]);
                s += f0 * f0 + f1 * f1 + f2 * f2 + f3 * f3;
            }
            float rn = 1.f / fmaxf(sqrtf(s), 1e-12f);
            if (pqk == 0) rn *= __expf(fminf(logit_scale[h], 4.605170185988091f));
            #pragma unroll
            for (int j = 0; j < 8; ++j) {
                v0[j] = (short)f2bf(bf2f((unsigned short)v0[j]) * rn);
                v1[j] = (short)f2bf(bf2f((unsigned short)v1[j]) * rn);
                v2[j] = (short)f2bf(bf2f((unsigned short)v2[j]) * rn);
                v3[j] = (short)f2bf(bf2f((unsigned short)v3[j]) * rn);
            }
            *(shortx8*)(p) = v0; *(shortx8*)(p + 8) = v1;
            *(shortx8*)(p + 16) = v2; *(shortx8*)(p + 24) = v3;
        }
    }
    __syncthreads();

    // ---- Phase 3: per-head attention (waves: h = wave, wave+4) ----
    {
        const float* maskw = mask + (size_t)(b & 63) * 4096;
        for (int h = wave; h < 6; h += 4) {
            const float* rpbh = rpb + h * 4096;
            shortx8 kf[4];                          // B frags of K (n = key token)
            #pragma unroll
            for (int nt = 0; nt < 4; ++nt)
                kf[nt] = *(const shortx8*)&QKVs[1][(nt * 16 + c) * LDA + h * 32 + qd * 8];
            shortx8 vf[2][2];                       // B frags of V: [k-step over keys][d-tile]
            #pragma unroll
            for (int kn = 0; kn < 2; ++kn)
                #pragma unroll
                for (int nd = 0; nd < 2; ++nd) {
                    shortx8 t;
                    #pragma unroll
                    for (int j = 0; j < 8; ++j)
                        t[j] = (short)QKVs[2][(kn * 32 + qd * 8 + j) * LDA + h * 32 + nd * 16 + c];
                    vf[kn][nd] = t;
                }
            for (int mt = 0; mt < 4; ++mt) {
                shortx8 qf = *(const shortx8*)&QKVs[0][(mt * 16 + c) * LDA + h * 32 + qd * 8];
                floatx4 a[4];
                #pragma unroll
                for (int nt = 0; nt < 4; ++nt) {
                    floatx4 z = (floatx4){0.f, 0.f, 0.f, 0.f};
                    a[nt] = __builtin_amdgcn_mfma_f32_16x16x32_bf16(qf, kf[nt], z, 0, 0, 0);
                }
                // softmax over the 64 cols of rows qd*4+r (16-lane groups share a row)
                #pragma unroll
                for (int r = 0; r < 4; ++r) {
                    int row = mt * 16 + qd * 4 + r;
                    float vals[4], vmax = -1e30f;
                    #pragma unroll
                    for (int nt = 0; nt < 4; ++nt) {
                        int col = nt * 16 + c;
                        float v = a[nt][r] + rpbh[row * 64 + col] + maskw[row * 64 + col];
                        vals[nt] = v; vmax = fmaxf(vmax, v);
                    }
                    #pragma unroll
                    for (int off = 1; off < 16; off <<= 1)
                        vmax = fmaxf(vmax, __shfl_xor(vmax, off, 16));
                    float ssum = 0.f;
                    #pragma unroll
                    for (int nt = 0; nt < 4; ++nt) {
                        float e = __expf(vals[nt] - vmax);
                        vals[nt] = e; ssum += e;
                    }
                    #pragma unroll
                    for (int off = 1; off < 16; off <<= 1)
                        ssum += __shfl_xor(ssum, off, 16);
                    float inv = 1.f / ssum;
                    #pragma unroll
                    for (int nt = 0; nt < 4; ++nt)
                        Ps[wave][(qd * 4 + r) * LDP + nt * 16 + c] = f2bf(vals[nt] * inv);
                }
                asm volatile("s_waitcnt lgkmcnt(0)" ::: "memory");  // P writes -> A-frag reads (in-wave)
                shortx8 pf[2];
                #pragma unroll
                for (int kn = 0; kn < 2; ++kn)
                    pf[kn] = *(const shortx8*)&Ps[wave][c * LDP + kn * 32 + qd * 8];
                #pragma unroll
                for (int nd = 0; nd < 2; ++nd) {
                    floatx4 o = (floatx4){0.f, 0.f, 0.f, 0.f};
                    o = __builtin_amdgcn_mfma_f32_16x16x32_bf16(pf[0], vf[0][nd], o, 0, 0, 0);
                    o = __builtin_amdgcn_mfma_f32_16x16x32_bf16(pf[1], vf[1][nd], o, 0, 0, 0);
                    #pragma unroll
                    for (int r = 0; r < 4; ++r)    // O -> Xs (x staging is dead), token-major
                        Xs[(mt * 16 + qd * 4 + r) * LDA + h * 32 + nd * 16 + c] = f2bf(o[r]);
                }
                asm volatile("s_waitcnt lgkmcnt(0)" ::: "memory");  // drain P reads before next mt overwrites
            }
        }
    }
    __syncthreads();

    // ---- Phase 4: proj GEMM (64x192)@(192x192) + bias -> out (f32) ----
    {
        shortx8 of[4][6];
        #pragma unroll
        for (int mt = 0; mt < 4; ++mt)
            #pragma unroll
            for (int ks = 0; ks < 6; ++ks)
                of[mt][ks] = *(const shortx8*)&Xs[(mt * 16 + c) * LDA + ks * 32 + qd * 8];
        float* outw = out + (size_t)b * 12288;
        #pragma unroll
        for (int nti = 0; nti < 3; ++nti) {
            int nt = wave * 3 + nti;
            const unsigned short* bp = projw + (nt * 16 + c) * 192 + qd * 8;
            shortx8 bf[6];
            #pragma unroll
            for (int ks = 0; ks < 6; ++ks) bf[ks] = *(const shortx8*)(bp + ks * 32);
            floatx4 acc[4];
            #pragma unroll
            for (int mt = 0; mt < 4; ++mt) acc[mt] = (floatx4){0.f, 0.f, 0.f, 0.f};
            #pragma unroll
            for (int ks = 0; ks < 6; ++ks)
                #pragma unroll
                for (int mt = 0; mt < 4; ++mt)
                    acc[mt] = __builtin_amdgcn_mfma_f32_16x16x32_bf16(of[mt][ks], bf[ks], acc[mt], 0, 0, 0);
            int gcol = nt * 16 + c;
            float bias = projb[gcol];
            #pragma unroll
            for (int mt = 0; mt < 4; ++mt)
                #pragma unroll
                for (int r = 0; r < 4; ++r)
                    outw[(mt * 16 + qd * 4 + r) * 192 + gcol] = acc[mt][r] + bias;
        }
    }
}

extern "C" void kernel_launch(void* const* d_in, const int* in_sizes, int n_in,
                              void* d_out, int out_size, void* d_ws, size_t ws_size,
                              hipStream_t stream) {
    const float* x           = (const float*)d_in[0];
    const float* mask        = (const float*)d_in[1];
    const float* qkv_w       = (const float*)d_in[2];
    const float* q_bias      = (const float*)d_in[3];
    const float* v_bias      = (const float*)d_in[4];
    const float* logit_scale = (const float*)d_in[5];
    const float* cpb_w1      = (const float*)d_in[6];
    const float* cpb_b1      = (const float*)d_in[7];
    const float* cpb_w2      = (const float*)d_in[8];
    const float* proj_w      = (const float*)d_in[9];
    const float* proj_b      = (const float*)d_in[10];
    const float* rct         = (const float*)d_in[11];
    const int*   rpi         = (const int*)d_in[12];

    char* ws = (char*)d_ws;
    unsigned short* qkvw_bf = (unsigned short*)ws;              // 221,184 B
    unsigned short* projw_bf = (unsigned short*)(ws + 221184);  //  73,728 B
    float* qkvb = (float*)(ws + 294912);                        //   2,304 B
    float* rpb  = (float*)(ws + 297216);                        //  98,304 B  (total 395,520 B)

    prep_weights<<<64, 256, 0, stream>>>(qkv_w, proj_w, q_bias, v_bias, qkvw_bf, projw_bf, qkvb);
    prep_cpb<<<1, 256, 0, stream>>>(cpb_w1, cpb_b1, cpb_w2, rct, rpi, rpb);
    win_attn<<<4096, 256, 0, stream>>>(x, mask, logit_scale, qkvw_bf, projw_bf,
                                       qkvb, proj_b, rpb, (float*)d_out);
}

// Round 2
// 591.511 us; speedup vs baseline: 1.4864x; 1.4864x over previous
//
#include <hip/hip_runtime.h>

// SwinV2 window attention, fully fused: one block = one window (64 tokens x 192 dim).
// R2: 768 threads (12 waves, 3/SIMD), V transposed in LDS for b128 PV frags,
// rpb+mask prefetch, parallel CPB prep. LDS = 132,096 B (1 block/CU).

#define LDA 200   // padded row stride (ushorts): 400B = 100 dwords -> 2-way bank aliasing only
#define LDV 72    // Vt row stride (ushorts): dim-major, 16B-aligned rows, 2-way aliasing
#define LDP 72    // P tile row stride

typedef __attribute__((ext_vector_type(4))) float floatx4;
typedef __attribute__((ext_vector_type(8))) short shortx8;
typedef __attribute__((ext_vector_type(4))) unsigned short ushortx4;

__device__ __forceinline__ unsigned short f2bf(float f) {
    union { float f; unsigned u; } v; v.f = f;
    return (unsigned short)((v.u + 0x7fffu + ((v.u >> 16) & 1u)) >> 16);  // RNE
}
__device__ __forceinline__ float bf2f(unsigned short s) {
    union { unsigned u; float f; } v; v.u = ((unsigned)s) << 16;
    return v.f;
}

// ---------------- prep: weights -> bf16, qkv bias concat ----------------
__global__ void prep_weights(const float* __restrict__ qkv_w,
                             const float* __restrict__ proj_w,
                             const float* __restrict__ q_bias,
                             const float* __restrict__ v_bias,
                             unsigned short* __restrict__ qkvw_bf,
                             unsigned short* __restrict__ projw_bf,
                             float* __restrict__ qkvb) {
    int stride = gridDim.x * blockDim.x;
    for (int i = blockIdx.x * blockDim.x + threadIdx.x; i < 110592 + 36864 + 576; i += stride) {
        if (i < 110592) {
            qkvw_bf[i] = f2bf(qkv_w[i]);
        } else if (i < 110592 + 36864) {
            projw_bf[i - 110592] = f2bf(proj_w[i - 110592]);
        } else {
            int j = i - 110592 - 36864;
            qkvb[j] = (j < 192) ? q_bias[j] : (j < 384 ? 0.f : v_bias[j - 384]);
        }
    }
}

// ---------------- prep: CPB MLP table, one wave per (pos, head) ----------------
__global__ void prep_cpb_tbl(const float* __restrict__ w1, const float* __restrict__ b1,
                             const float* __restrict__ w2, const float* __restrict__ rct,
                             float* __restrict__ tbls) {
    int wave = threadIdx.x >> 6, lane = threadIdx.x & 63;
    int pr = blockIdx.x * 4 + wave;                  // 225 positions x 6 heads = 1350
    if (pr >= 1350) return;
    int p = pr / 6, h = pr - p * 6;
    float c0 = rct[p * 2], c1 = rct[p * 2 + 1];
    float s = 0.f;
    #pragma unroll
    for (int it = 0; it < 8; ++it) {
        int j = lane + it * 64;
        float hv = fmaxf(0.f, c0 * w1[j * 2] + c1 * w1[j * 2 + 1] + b1[j]);
        s += hv * w2[h * 512 + j];
    }
    #pragma unroll
    for (int off = 32; off >= 1; off >>= 1) s += __shfl_xor(s, off);
    if (lane == 0) tbls[pr] = s;                     // [p][h]
}

// ---------------- prep: gather -> rpb[6][64][64] = 16*sigmoid ----------------
__global__ void prep_cpb_gather(const float* __restrict__ tbls, const int* __restrict__ rpi,
                                float* __restrict__ rpb) {
    int e = blockIdx.x * 256 + threadIdx.x;          // 6*64*64 = 24576
    if (e >= 24576) return;
    // rel_pos_index may arrive as int64 (little-endian pairs) or int32; rpi[1]==0 iff int64.
    int stride64 = (rpi[1] == 0) ? 2 : 1;
    int h = e >> 12, rc = e & 4095;
    int idx = rpi[rc * stride64];
    float t = tbls[idx * 6 + h];
    rpb[e] = 16.f / (1.f + __expf(-t));
}

// ---------------- main fused kernel ----------------
__global__ __launch_bounds__(768, 3) void win_attn(
    const float* __restrict__ x, const float* __restrict__ mask,
    const float* __restrict__ logit_scale,
    const unsigned short* __restrict__ qkvw, const unsigned short* __restrict__ projw,
    const float* __restrict__ qkvb, const float* __restrict__ projb,
    const float* __restrict__ rpb, float* __restrict__ out)
{
    __shared__ unsigned short Xs[64 * LDA];        // 25,600 B: x staging; later attn output O
    __shared__ unsigned short Qs[64 * LDA];        // 25,600 B
    __shared__ unsigned short Ks[64 * LDA];        // 25,600 B
    __shared__ unsigned short Vt[192 * LDV];       // 27,648 B: V transposed [dim][token]
    __shared__ unsigned short Ps[12][16 * LDP];    // 27,648 B: per-wave 16x64 P tile

    const int tid  = threadIdx.x;
    const int b    = blockIdx.x;
    const int wave = tid >> 6, lane = tid & 63;
    const int c = lane & 15, qd = lane >> 4;       // MFMA lane coords: col / quad

    // ---- Phase 0: stage x window (f32 -> bf16 LDS) ----
    {
        const float4* xw = (const float4*)(x + (size_t)b * 12288);
        for (int i = tid; i < 3072; i += 768) {
            float4 v = xw[i];
            int token = i / 48, c4 = (i - token * 48) * 4;
            ushortx4 u = { f2bf(v.x), f2bf(v.y), f2bf(v.z), f2bf(v.w) };
            *(ushortx4*)&Xs[token * LDA + c4] = u;
        }
    }
    __syncthreads();

    // ---- Phase 1: QKV GEMM (64x192)@(192x576), 36 n-tiles = 3/wave ----
    {
        for (int nti = 0; nti < 3; ++nti) {
            int nt = wave * 3 + nti;
            const unsigned short* bp = qkvw + (nt * 16 + c) * 192 + qd * 8;
            shortx8 bf[6];
            #pragma unroll
            for (int ks = 0; ks < 6; ++ks) bf[ks] = *(const shortx8*)(bp + ks * 32);
            int gcol = nt * 16 + c;
            int part = nt / 12;                    // 0=q, 1=k, 2=v
            int inner = gcol - part * 192;
            float bias = qkvb[gcol];
            #pragma unroll
            for (int mh = 0; mh < 2; ++mh) {       // two 32-row halves: keeps VGPRs under 3-wave cap
                shortx8 af[2][6];
                #pragma unroll
                for (int mi = 0; mi < 2; ++mi)
                    #pragma unroll
                    for (int ks = 0; ks < 6; ++ks)
                        af[mi][ks] = *(const shortx8*)&Xs[((mh * 2 + mi) * 16 + c) * LDA + ks * 32 + qd * 8];
                floatx4 acc[2];
                acc[0] = (floatx4){0.f, 0.f, 0.f, 0.f};
                acc[1] = (floatx4){0.f, 0.f, 0.f, 0.f};
                #pragma unroll
                for (int ks = 0; ks < 6; ++ks)
                    #pragma unroll
                    for (int mi = 0; mi < 2; ++mi)
                        acc[mi] = __builtin_amdgcn_mfma_f32_16x16x32_bf16(af[mi][ks], bf[ks], acc[mi], 0, 0, 0);
                #pragma unroll
                for (int mi = 0; mi < 2; ++mi)
                    #pragma unroll
                    for (int r = 0; r < 4; ++r) {  // C/D layout: row = qd*4+r, col = c
                        int row = (mh * 2 + mi) * 16 + qd * 4 + r;
                        unsigned short bv = f2bf(acc[mi][r] + bias);
                        if (part == 2) Vt[inner * LDV + row] = bv;           // transposed store
                        else if (part == 1) Ks[row * LDA + inner] = bv;
                        else Qs[row * LDA + inner] = bv;
                    }
            }
        }
    }
    __syncthreads();

    // ---- Phase 2: L2-normalize q,k per (head, token); fold exp(min(ls, ln100)) into q ----
    {
        int idx = tid;                              // 2 parts x 6 heads x 64 tokens = 768 exactly
        int pqk = idx / 384, rem = idx - pqk * 384;
        int h = rem >> 6, token = rem & 63;
        unsigned short* p = (pqk == 0 ? Qs : Ks) + token * LDA + h * 32;
        shortx8 v0 = *(shortx8*)(p),      v1 = *(shortx8*)(p + 8),
                v2 = *(shortx8*)(p + 16), v3 = *(shortx8*)(p + 24);
        float s = 0.f;
        #pragma unroll
        for (int j = 0; j < 8; ++j) {
            float f0 = bf2f((unsigned short)v0[j]), f1 = bf2f((unsigned short)v1[j]);
            float f2 = bf2f((unsigned short)v2[j]), f3 = bf2f((unsigned short)v3[j]);
            s += f0 * f0 + f1 * f1 + f2 * f2 + f3 * f3;
        }
        float rn = 1.f / fmaxf(sqrtf(s), 1e-12f);
        if (pqk == 0) rn *= __expf(fminf(logit_scale[h], 4.605170185988091f));
        #pragma unroll
        for (int j = 0; j < 8; ++j) {
            v0[j] = (short)f2bf(bf2f((unsigned short)v0[j]) * rn);
            v1[j] = (short)f2bf(bf2f((unsigned short)v1[j]) * rn);
            v2[j] = (short)f2bf(bf2f((unsigned short)v2[j]) * rn);
            v3[j] = (short)f2bf(bf2f((unsigned short)v3[j]) * rn);
        }
        *(shortx8*)(p) = v0; *(shortx8*)(p + 8) = v1;
        *(shortx8*)(p + 16) = v2; *(shortx8*)(p + 24) = v3;
    }
    __syncthreads();

    // ---- Phase 3: attention; 24 (head, m-tile) units = 2/wave, one head per wave ----
    {
        const float* maskw = mask + (size_t)(b & 63) * 4096;
        const int h = wave >> 1;
        const float* rpbh = rpb + h * 4096;
        shortx8 kf[4];                              // B frags of K (n = key token)
        #pragma unroll
        for (int nt = 0; nt < 4; ++nt)
            kf[nt] = *(const shortx8*)&Ks[(nt * 16 + c) * LDA + h * 32 + qd * 8];
        shortx8 vf[2][2];                           // B frags of V from Vt: all b128
        #pragma unroll
        for (int kn = 0; kn < 2; ++kn)
            #pragma unroll
            for (int nd = 0; nd < 2; ++nd)
                vf[kn][nd] = *(const shortx8*)&Vt[(h * 32 + nd * 16 + c) * LDV + kn * 32 + qd * 8];
        #pragma unroll
        for (int mti = 0; mti < 2; ++mti) {
            int mt = (wave & 1) * 2 + mti;
            float rm[4][4];                         // rpb+mask prefetch (L2 latency overlaps MFMA)
            #pragma unroll
            for (int r = 0; r < 4; ++r) {
                int row = mt * 16 + qd * 4 + r;
                #pragma unroll
                for (int nt = 0; nt < 4; ++nt) {
                    int col = nt * 16 + c;
                    rm[r][nt] = rpbh[row * 64 + col] + maskw[row * 64 + col];
                }
            }
            shortx8 qf = *(const shortx8*)&Qs[(mt * 16 + c) * LDA + h * 32 + qd * 8];
            floatx4 a[4];
            #pragma unroll
            for (int nt = 0; nt < 4; ++nt) {
                floatx4 z = (floatx4){0.f, 0.f, 0.f, 0.f};
                a[nt] = __builtin_amdgcn_mfma_f32_16x16x32_bf16(qf, kf[nt], z, 0, 0, 0);
            }
            // softmax over 64 cols of rows qd*4+r (16-lane groups share a row)
            #pragma unroll
            for (int r = 0; r < 4; ++r) {
                float vals[4], vmax = -1e30f;
                #pragma unroll
                for (int nt = 0; nt < 4; ++nt) {
                    float v = a[nt][r] + rm[r][nt];
                    vals[nt] = v; vmax = fmaxf(vmax, v);
                }
                #pragma unroll
                for (int off = 1; off < 16; off <<= 1)
                    vmax = fmaxf(vmax, __shfl_xor(vmax, off, 16));
                float ssum = 0.f;
                #pragma unroll
                for (int nt = 0; nt < 4; ++nt) {
                    float e = __expf(vals[nt] - vmax);
                    vals[nt] = e; ssum += e;
                }
                #pragma unroll
                for (int off = 1; off < 16; off <<= 1)
                    ssum += __shfl_xor(ssum, off, 16);
                float inv = 1.f / ssum;
                #pragma unroll
                for (int nt = 0; nt < 4; ++nt)
                    Ps[wave][(qd * 4 + r) * LDP + nt * 16 + c] = f2bf(vals[nt] * inv);
            }
            asm volatile("s_waitcnt lgkmcnt(0)" ::: "memory");  // P writes land before A-frag reads
            shortx8 pf[2];
            #pragma unroll
            for (int kn = 0; kn < 2; ++kn)
                pf[kn] = *(const shortx8*)&Ps[wave][c * LDP + kn * 32 + qd * 8];
            #pragma unroll
            for (int nd = 0; nd < 2; ++nd) {
                floatx4 o = (floatx4){0.f, 0.f, 0.f, 0.f};
                o = __builtin_amdgcn_mfma_f32_16x16x32_bf16(pf[0], vf[0][nd], o, 0, 0, 0);
                o = __builtin_amdgcn_mfma_f32_16x16x32_bf16(pf[1], vf[1][nd], o, 0, 0, 0);
                #pragma unroll
                for (int r = 0; r < 4; ++r)        // O -> Xs (x staging is dead)
                    Xs[(mt * 16 + qd * 4 + r) * LDA + h * 32 + nd * 16 + c] = f2bf(o[r]);
            }
            // no drain needed: pf reads complete before the PV MFMAs issue (compiler waitcnt),
            // and next iteration's P writes come after those MFMAs.
        }
    }
    __syncthreads();

    // ---- Phase 4: proj GEMM (64x192)@(192x192) + bias -> out; 12 n-tiles = 1/wave ----
    {
        const int nt = wave;
        const unsigned short* bp = projw + (nt * 16 + c) * 192 + qd * 8;
        shortx8 bf[6];
        #pragma unroll
        for (int ks = 0; ks < 6; ++ks) bf[ks] = *(const shortx8*)(bp + ks * 32);
        int gcol = nt * 16 + c;
        float bias = projb[gcol];
        float* outw = out + (size_t)b * 12288;
        #pragma unroll
        for (int mh = 0; mh < 2; ++mh) {
            shortx8 af[2][6];
            #pragma unroll
            for (int mi = 0; mi < 2; ++mi)
                #pragma unroll
                for (int ks = 0; ks < 6; ++ks)
                    af[mi][ks] = *(const shortx8*)&Xs[((mh * 2 + mi) * 16 + c) * LDA + ks * 32 + qd * 8];
            floatx4 acc[2];
            acc[0] = (floatx4){0.f, 0.f, 0.f, 0.f};
            acc[1] = (floatx4){0.f, 0.f, 0.f, 0.f};
            #pragma unroll
            for (int ks = 0; ks < 6; ++ks)
                #pragma unroll
                for (int mi = 0; mi < 2; ++mi)
                    acc[mi] = __builtin_amdgcn_mfma_f32_16x16x32_bf16(af[mi][ks], bf[ks], acc[mi], 0, 0, 0);
            #pragma unroll
            for (int mi = 0; mi < 2; ++mi)
                #pragma unroll
                for (int r = 0; r < 4; ++r)
                    outw[((mh * 2 + mi) * 16 + qd * 4 + r) * 192 + gcol] = acc[mi][r] + bias;
        }
    }
}

extern "C" void kernel_launch(void* const* d_in, const int* in_sizes, int n_in,
                              void* d_out, int out_size, void* d_ws, size_t ws_size,
                              hipStream_t stream) {
    const float* x           = (const float*)d_in[0];
    const float* mask        = (const float*)d_in[1];
    const float* qkv_w       = (const float*)d_in[2];
    const float* q_bias      = (const float*)d_in[3];
    const float* v_bias      = (const float*)d_in[4];
    const float* logit_scale = (const float*)d_in[5];
    const float* cpb_w1      = (const float*)d_in[6];
    const float* cpb_b1      = (const float*)d_in[7];
    const float* cpb_w2      = (const float*)d_in[8];
    const float* proj_w      = (const float*)d_in[9];
    const float* proj_b      = (const float*)d_in[10];
    const float* rct         = (const float*)d_in[11];
    const int*   rpi         = (const int*)d_in[12];

    char* ws = (char*)d_ws;
    unsigned short* qkvw_bf  = (unsigned short*)ws;             // 221,184 B
    unsigned short* projw_bf = (unsigned short*)(ws + 221184);  //  73,728 B
    float* qkvb = (float*)(ws + 294912);                        //   2,304 B
    float* rpb  = (float*)(ws + 297216);                        //  98,304 B
    float* tbls = (float*)(ws + 395520);                        //   5,400 B (total 400,920 B)

    prep_weights<<<64, 256, 0, stream>>>(qkv_w, proj_w, q_bias, v_bias, qkvw_bf, projw_bf, qkvb);
    prep_cpb_tbl<<<338, 256, 0, stream>>>(cpb_w1, cpb_b1, cpb_w2, rct, tbls);
    prep_cpb_gather<<<96, 256, 0, stream>>>(tbls, rpi, rpb);
    win_attn<<<4096, 768, 0, stream>>>(x, mask, logit_scale, qkvw_bf, projw_bf,
                                       qkvb, proj_b, rpb, (float*)d_out);
}